// Round 5
// baseline (79.190 us; speedup 1.0000x reference)
//
#include <hip/hip_runtime.h>
#include <hip/hip_bf16.h>

#define N_FEATURES 4096
#define N_ACTIONS 4
#define N_CPA 10
#define N_CLAUSES 40
#define BATCH 16384
#define EPS 1e-8f
#define ACTIVE_THRESH 1e-6f

typedef float f4v __attribute__((ext_vector_type(4)));

// Fast, self-consistent w computation (identical code in both setup kernels).
__device__ __forceinline__ void compute_w4(const float4 u4, const float4 m4,
                                           const float4 c4, const float invt,
                                           bool pos[4], bool neg[4]) {
    const float uu[4] = {u4.x, u4.y, u4.z, u4.w};
    const float mm[4] = {m4.x, m4.y, m4.z, m4.w};
    const float ww[4] = {c4.x, c4.y, c4.z, c4.w};
    #pragma unroll
    for (int e = 0; e < 4; ++e) {
        float z = (__logf((uu[e] + EPS) / (1.0f - uu[e] + EPS)) + mm[e]) * invt;
        float s = 1.0f / (1.0f + __expf(-z));
        float w = tanhf(ww[e] * invt) * s;
        bool active = fabsf(w) > ACTIVE_THRESH;
        pos[e] = active && (w > 0.0f);
        neg[e] = active && !(w > 0.0f);
    }
}

// ---------------- Kernel A: per-block partial pos/neg counts ----------------
// 16 blocks x 256 threads, thread-per-feature. Coalesced contiguous reads,
// counts via ballot+popcount (no atomics, no memset).
__global__ void count_kernel(const float* __restrict__ cw,
                             const float* __restrict__ ml,
                             const float* __restrict__ u,
                             const float* __restrict__ tptr,
                             float* __restrict__ part_pos,  // [16][40]
                             float* __restrict__ part_neg)  // [16][40]
{
    __shared__ float spw[4][N_CLAUSES], snw[4][N_CLAUSES];
    const int tid = threadIdx.x, wave = tid >> 6, lane = tid & 63;
    const int f = blockIdx.x * 256 + tid;
    const float invt = 1.0f / (tptr[0] + EPS);

    const float4* ub = (const float4*)(u  + (size_t)f * N_CLAUSES);
    const float4* mb = (const float4*)(ml + (size_t)f * N_CLAUSES);
    const float4* cb = (const float4*)(cw + (size_t)f * N_CLAUSES);

    #pragma unroll
    for (int cq = 0; cq < N_CLAUSES / 4; ++cq) {
        bool pos[4], neg[4];
        compute_w4(ub[cq], mb[cq], cb[cq], invt, pos, neg);
        #pragma unroll
        for (int e = 0; e < 4; ++e) {
            unsigned long long bp = __ballot(pos[e]);
            unsigned long long bn = __ballot(neg[e]);
            if (lane == 0) {
                spw[wave][cq * 4 + e] = (float)__popcll(bp);
                snw[wave][cq * 4 + e] = (float)__popcll(bn);
            }
        }
    }
    __syncthreads();
    if (tid < N_CLAUSES) {
        float p = spw[0][tid] + spw[1][tid] + spw[2][tid] + spw[3][tid];
        float n = snw[0][tid] + snw[1][tid] + snw[2][tid] + snw[3][tid];
        part_pos[blockIdx.x * N_CLAUSES + tid] = p;
        part_neg[blockIdx.x * N_CLAUSES + tid] = n;
    }
}

// ---------------- Kernel B: fold directly into D planes + K ----------------
// 16 blocks x 256 threads, thread-per-feature; recomputes w (identical code).
__global__ void fold_kernel(const float* __restrict__ cw,
                            const float* __restrict__ ml,
                            const float* __restrict__ u,
                            const float* __restrict__ tptr,
                            const float* __restrict__ part_pos,
                            const float* __restrict__ part_neg,
                            float* __restrict__ D,   // [4][4096]
                            float* __restrict__ K)   // [4]
{
    __shared__ float sinv[N_CLAUSES], sneg[N_CLAUSES];
    const int tid = threadIdx.x;
    if (tid < N_CLAUSES) {
        float p = 0.0f, n = 0.0f;
        #pragma unroll
        for (int b = 0; b < 16; ++b) {
            p += part_pos[b * N_CLAUSES + tid];
            n += part_neg[b * N_CLAUSES + tid];
        }
        float cn = p + n;
        sinv[tid] = (cn > 0.0f) ? (1.0f / cn) : 0.0f;
        sneg[tid] = n;
    }
    __syncthreads();

    const int f = blockIdx.x * 256 + tid;
    const float invt = 1.0f / (tptr[0] + EPS);
    const float4* ub = (const float4*)(u  + (size_t)f * N_CLAUSES);
    const float4* mb = (const float4*)(ml + (size_t)f * N_CLAUSES);
    const float4* cb = (const float4*)(cw + (size_t)f * N_CLAUSES);

    float acc[N_ACTIONS] = {0.0f, 0.0f, 0.0f, 0.0f};
    #pragma unroll
    for (int cq = 0; cq < N_CLAUSES / 4; ++cq) {
        bool pos[4], neg[4];
        compute_w4(ub[cq], mb[cq], cb[cq], invt, pos, neg);
        #pragma unroll
        for (int e = 0; e < 4; ++e) {
            const int c = cq * 4 + e;            // compile-time constant
            float d = pos[e] ? 1.0f : (neg[e] ? -1.0f : 0.0f);
            acc[c / N_CPA] += d * sinv[c];
        }
    }
    #pragma unroll
    for (int a = 0; a < N_ACTIONS; ++a)
        D[a * N_FEATURES + f] = acc[a];

    if (blockIdx.x == 0 && tid < N_ACTIONS) {
        float k = 0.0f;
        #pragma unroll
        for (int j = 0; j < N_CPA; ++j) {
            const int c = tid * N_CPA + j;
            k += (sinv[c] > 0.0f) ? (sneg[c] * sinv[c]) : 1.0f;
        }
        K[tid] = k;
    }
}

// ---------------- Kernel 3: out = X @ D + K, barrier-free main loop ----------------
// block = 256 threads covers a full 4096-feature row (thread: 4 float4 chunks @ stride 1024).
// 8 rows per block, 32 accumulators/thread, double-buffered row loads, ONE reduce tail.
#define RPB 8

__global__ __launch_bounds__(256, 3) void gemv_kernel(const float* __restrict__ x,
                                                      const float* __restrict__ D,
                                                      const float* __restrict__ K,
                                                      float* __restrict__ out)
{
    const int tid  = threadIdx.x;
    const int wave = tid >> 6;
    const int lane = tid & 63;

    __shared__ float red[4][32];

    // register-resident D fragment: [chunk][action] float4 (64 VGPRs)
    f4v Dr[4][4];
    #pragma unroll
    for (int c = 0; c < 4; ++c)
        #pragma unroll
        for (int a = 0; a < 4; ++a)
            Dr[c][a] = *(const f4v*)(D + a * N_FEATURES + (c * 256 + tid) * 4);

    const int rb = blockIdx.x * RPB;
    const f4v* xrow = (const f4v*)(x + (size_t)rb * N_FEATURES);

    float acc[RPB][4];
    #pragma unroll
    for (int r = 0; r < RPB; ++r)
        #pragma unroll
        for (int a = 0; a < 4; ++a) acc[r][a] = 0.0f;

    // double-buffered x loads: issue row r+1 before consuming row r
    f4v xv[2][4];
    #pragma unroll
    for (int c = 0; c < 4; ++c)
        xv[0][c] = __builtin_nontemporal_load(&xrow[c * 256 + tid]);

    #pragma unroll
    for (int r = 0; r < RPB; ++r) {
        const int cur = r & 1, nxt = cur ^ 1;
        if (r + 1 < RPB) {
            #pragma unroll
            for (int c = 0; c < 4; ++c)
                xv[nxt][c] = __builtin_nontemporal_load(&xrow[(r + 1) * 1024 + c * 256 + tid]);
        }
        #pragma unroll
        for (int c = 0; c < 4; ++c) {
            const f4v xc = xv[cur][c];
            #pragma unroll
            for (int a = 0; a < 4; ++a)
                acc[r][a] += xc.x * Dr[c][a].x + xc.y * Dr[c][a].y
                           + xc.z * Dr[c][a].z + xc.w * Dr[c][a].w;
        }
    }

    // single reduce tail: butterfly all 32 values across the wave
    #pragma unroll
    for (int off = 32; off; off >>= 1)
        #pragma unroll
        for (int r = 0; r < RPB; ++r)
            #pragma unroll
            for (int a = 0; a < 4; ++a)
                acc[r][a] += __shfl_xor(acc[r][a], off);

    // lane v (v<32) carries value v = r*4+a (compile-time-indexed select)
    float myv = acc[0][0];
    #pragma unroll
    for (int v = 1; v < 32; ++v)
        if (lane == v) myv = acc[v >> 2][v & 3];
    if (lane < 32) red[wave][lane] = myv;
    __syncthreads();

    if (tid < 32) {
        float s = red[0][tid] + red[1][tid] + red[2][tid] + red[3][tid];
        out[rb * N_ACTIONS + tid] = s + K[tid & 3];   // 32 consecutive floats, coalesced
    }
}

extern "C" void kernel_launch(void* const* d_in, const int* in_sizes, int n_in,
                              void* d_out, int out_size, void* d_ws, size_t ws_size,
                              hipStream_t stream) {
    const float* features = (const float*)d_in[0];
    const float* cw       = (const float*)d_in[1];
    const float* ml       = (const float*)d_in[2];
    const float* u        = (const float*)d_in[3];
    const float* tptr     = (const float*)d_in[4];
    float* out = (float*)d_out;

    // workspace layout (floats)
    float* ws = (float*)d_ws;
    float* Dmat     = ws;                                  // 4*4096 (offset 0, aligned)
    float* K        = Dmat + N_ACTIONS * N_FEATURES;       // 4
    float* part_pos = K + 4;                               // 16*40
    float* part_neg = part_pos + 16 * N_CLAUSES;           // 16*40

    count_kernel<<<16, 256, 0, stream>>>(cw, ml, u, tptr, part_pos, part_neg);
    fold_kernel<<<16, 256, 0, stream>>>(cw, ml, u, tptr, part_pos, part_neg, Dmat, K);
    gemv_kernel<<<BATCH / RPB, 256, 0, stream>>>(features, Dmat, K, out);
}

// Round 6
// 58.658 us; speedup vs baseline: 1.3500x; 1.3500x over previous
//
#include <hip/hip_runtime.h>
#include <hip/hip_bf16.h>

#define N_FEATURES 4096
#define N_ACTIONS 4
#define N_CPA 10
#define N_CLAUSES 40
#define BATCH 16384
#define EPS 1e-8f
#define ACTIVE_THRESH 1e-6f
#define NBLK_A 160   // count_kernel blocks

typedef float f4v __attribute__((ext_vector_type(4)));

// ---------------- Phase A: flat coalesced pass, w computed ONCE ----------------
// 160 blocks x 256 threads; thread handles 4 consecutive elements (one float4 per
// array). Writes packed int8 ternary d and per-block partial pos/neg counts.
__global__ void count_kernel(const float* __restrict__ cw,
                             const float* __restrict__ ml,
                             const float* __restrict__ u,
                             const float* __restrict__ tptr,
                             signed char* __restrict__ d8,   // [4096*40] f-major, int8
                             float* __restrict__ part_pos,   // [160][40]
                             float* __restrict__ part_neg)   // [160][40]
{
    __shared__ float sp[N_CLAUSES], sn[N_CLAUSES];
    const int tid = threadIdx.x;
    if (tid < N_CLAUSES) { sp[tid] = 0.0f; sn[tid] = 0.0f; }
    __syncthreads();

    const float invt = 1.0f / (tptr[0] + EPS);
    const int i4 = blockIdx.x * 256 + tid;          // float4 index, 0..40959

    const float4 u4 = ((const float4*)u)[i4];
    const float4 m4 = ((const float4*)ml)[i4];
    const float4 c4 = ((const float4*)cw)[i4];

    const float uu[4] = {u4.x, u4.y, u4.z, u4.w};
    const float mm[4] = {m4.x, m4.y, m4.z, m4.w};
    const float ww[4] = {c4.x, c4.y, c4.z, c4.w};

    union { signed char c[4]; int i; } pk;
    #pragma unroll
    for (int e = 0; e < 4; ++e) {
        float z = (__logf((uu[e] + EPS) / (1.0f - uu[e] + EPS)) + mm[e]) * invt;
        float s = 1.0f / (1.0f + __expf(-z));
        float w = tanhf(ww[e] * invt) * s;
        bool active = fabsf(w) > ACTIVE_THRESH;
        bool pos = active && (w > 0.0f);
        bool neg = active && !(w > 0.0f);
        pk.c[e] = pos ? 1 : (neg ? -1 : 0);
        const int c = (i4 * 4 + e) % N_CLAUSES;
        if (pos) atomicAdd(&sp[c], 1.0f);
        if (neg) atomicAdd(&sn[c], 1.0f);
    }
    ((int*)d8)[i4] = pk.i;                           // coalesced 4B store

    __syncthreads();
    if (tid < N_CLAUSES) {
        part_pos[blockIdx.x * N_CLAUSES + tid] = sp[tid];
        part_neg[blockIdx.x * N_CLAUSES + tid] = sn[tid];
    }
}

// ---------------- Phase B: reduce partials, fold d into D planes + K ----------------
// 64 blocks x 256 threads, thread per (action, feature). No transcendentals.
__global__ void fold_kernel(const signed char* __restrict__ d8,
                            const float* __restrict__ part_pos,
                            const float* __restrict__ part_neg,
                            float* __restrict__ D,   // [4][4096]
                            float* __restrict__ K)   // [4]
{
    __shared__ float sinv[N_CLAUSES], sneg[N_CLAUSES];
    const int tid = threadIdx.x;
    if (tid < N_CLAUSES) {
        float p = 0.0f, n = 0.0f;
        for (int b = 0; b < NBLK_A; ++b) {
            p += part_pos[b * N_CLAUSES + tid];
            n += part_neg[b * N_CLAUSES + tid];
        }
        float cn = p + n;
        sinv[tid] = (cn > 0.0f) ? (1.0f / cn) : 0.0f;
        sneg[tid] = n;
    }
    __syncthreads();

    const int idx = blockIdx.x * 256 + tid;          // 0..16383
    const int f = idx & (N_FEATURES - 1);
    const int a = idx >> 12;

    const signed char* drow = d8 + (size_t)f * N_CLAUSES + a * N_CPA;
    float acc = 0.0f;
    #pragma unroll
    for (int j = 0; j < N_CPA; ++j) {
        const int c = a * N_CPA + j;                 // a is uniform per 4096-thread span
        acc += (float)drow[j] * sinv[c];
    }
    D[a * N_FEATURES + f] = acc;                     // coalesced

    if (blockIdx.x == 0 && tid < N_ACTIONS) {
        float k = 0.0f;
        #pragma unroll
        for (int j = 0; j < N_CPA; ++j) {
            const int c = tid * N_CPA + j;
            k += (sinv[c] > 0.0f) ? (sneg[c] * sinv[c]) : 1.0f;
        }
        K[tid] = k;
    }
}

// ---------------- Kernel 3: out = X @ D + K, barrier-free main loop ----------------
// (unchanged from round 4 — proven) block = 256 threads covers a full 4096-feature
// row; 8 rows/block, 32 acc/thread, double-buffered loads, ONE reduce tail.
#define RPB 8

__global__ __launch_bounds__(256, 3) void gemv_kernel(const float* __restrict__ x,
                                                      const float* __restrict__ D,
                                                      const float* __restrict__ K,
                                                      float* __restrict__ out)
{
    const int tid  = threadIdx.x;
    const int wave = tid >> 6;
    const int lane = tid & 63;

    __shared__ float red[4][32];

    // register-resident D fragment: [chunk][action] float4 (64 VGPRs)
    f4v Dr[4][4];
    #pragma unroll
    for (int c = 0; c < 4; ++c)
        #pragma unroll
        for (int a = 0; a < 4; ++a)
            Dr[c][a] = *(const f4v*)(D + a * N_FEATURES + (c * 256 + tid) * 4);

    const int rb = blockIdx.x * RPB;
    const f4v* xrow = (const f4v*)(x + (size_t)rb * N_FEATURES);

    float acc[RPB][4];
    #pragma unroll
    for (int r = 0; r < RPB; ++r)
        #pragma unroll
        for (int a = 0; a < 4; ++a) acc[r][a] = 0.0f;

    // double-buffered x loads: issue row r+1 before consuming row r
    f4v xv[2][4];
    #pragma unroll
    for (int c = 0; c < 4; ++c)
        xv[0][c] = __builtin_nontemporal_load(&xrow[c * 256 + tid]);

    #pragma unroll
    for (int r = 0; r < RPB; ++r) {
        const int cur = r & 1, nxt = cur ^ 1;
        if (r + 1 < RPB) {
            #pragma unroll
            for (int c = 0; c < 4; ++c)
                xv[nxt][c] = __builtin_nontemporal_load(&xrow[(r + 1) * 1024 + c * 256 + tid]);
        }
        #pragma unroll
        for (int c = 0; c < 4; ++c) {
            const f4v xc = xv[cur][c];
            #pragma unroll
            for (int a = 0; a < 4; ++a)
                acc[r][a] += xc.x * Dr[c][a].x + xc.y * Dr[c][a].y
                           + xc.z * Dr[c][a].z + xc.w * Dr[c][a].w;
        }
    }

    // single reduce tail: butterfly all 32 values across the wave
    #pragma unroll
    for (int off = 32; off; off >>= 1)
        #pragma unroll
        for (int r = 0; r < RPB; ++r)
            #pragma unroll
            for (int a = 0; a < 4; ++a)
                acc[r][a] += __shfl_xor(acc[r][a], off);

    // lane v (v<32) carries value v = r*4+a (compile-time-indexed select)
    float myv = acc[0][0];
    #pragma unroll
    for (int v = 1; v < 32; ++v)
        if (lane == v) myv = acc[v >> 2][v & 3];
    if (lane < 32) red[wave][lane] = myv;
    __syncthreads();

    if (tid < 32) {
        float s = red[0][tid] + red[1][tid] + red[2][tid] + red[3][tid];
        out[rb * N_ACTIONS + tid] = s + K[tid & 3];   // 32 consecutive floats, coalesced
    }
}

extern "C" void kernel_launch(void* const* d_in, const int* in_sizes, int n_in,
                              void* d_out, int out_size, void* d_ws, size_t ws_size,
                              hipStream_t stream) {
    const float* features = (const float*)d_in[0];
    const float* cw       = (const float*)d_in[1];
    const float* ml       = (const float*)d_in[2];
    const float* u        = (const float*)d_in[3];
    const float* tptr     = (const float*)d_in[4];
    float* out = (float*)d_out;

    // workspace layout (~282 KB total)
    float* ws = (float*)d_ws;
    float* Dmat     = ws;                                   // 16384 floats
    float* K        = Dmat + N_ACTIONS * N_FEATURES;        // 4
    float* part_pos = K + 4;                                // 160*40
    float* part_neg = part_pos + NBLK_A * N_CLAUSES;        // 160*40
    signed char* d8 = (signed char*)(part_neg + NBLK_A * N_CLAUSES); // 163840 B (4B-aligned)

    count_kernel<<<NBLK_A, 256, 0, stream>>>(cw, ml, u, tptr, d8, part_pos, part_neg);
    fold_kernel<<<(N_ACTIONS * N_FEATURES) / 256, 256, 0, stream>>>(d8, part_pos, part_neg, Dmat, K);
    gemv_kernel<<<BATCH / RPB, 256, 0, stream>>>(features, Dmat, K, out);
}